// Round 2
// baseline (5175.364 us; speedup 1.0000x reference)
//
#include <hip/hip_runtime.h>
#include <hip/hip_bf16.h>
#include <math.h>

#define NNODE 200000
#define EMBD  128
#define TT    32
#define EE    100000
#define AA    4096
#define BB    2048
#define USERN 150000
#define COMPN 49998

// order-preserving float<->uint mapping for atomicMax on mixed-sign floats
__device__ __forceinline__ unsigned floatToOrd(float f) {
    unsigned b = __float_as_uint(f);
    return (b & 0x80000000u) ? ~b : (b | 0x80000000u);
}
__device__ __forceinline__ float ordToFloat(unsigned u) {
    return (u & 0x80000000u) ? __uint_as_float(u & 0x7fffffffu) : __uint_as_float(~u);
}

// ---------------- init ----------------
__global__ void init_kernel(const float4* __restrict__ ent, const float4* __restrict__ c0,
                            float4* __restrict__ node, float4* __restrict__ cxp,
                            float4* __restrict__ msg, float* __restrict__ cnt,
                            float* __restrict__ s_tot, unsigned* __restrict__ m_ord,
                            float* __restrict__ out) {
    const long NV = (long)NNODE * EMBD / 4;  // 6.4M float4
    long i0 = (long)blockIdx.x * blockDim.x + threadIdx.x;
    long stride = (long)gridDim.x * blockDim.x;
    float4 z = make_float4(0.f, 0.f, 0.f, 0.f);
    for (long i = i0; i < NV; i += stride) { node[i] = ent[i]; cxp[i] = c0[i]; msg[i] = z; }
    for (long i = i0; i < NNODE; i += stride) cnt[i] = 0.f;
    for (long i = i0; i < BB; i += stride) { s_tot[i] = 0.f; m_ord[i] = 0u; }
    if (i0 == 0) out[0] = 0.f;
}

// ---------------- per-step: edge scatter ----------------
__global__ void edge_kernel(const int* __restrict__ src, const int* __restrict__ dst,
                            const float* __restrict__ node, float* __restrict__ msg,
                            float* __restrict__ cnt) {
    int e = blockIdx.x * 2 + threadIdx.x / 128;
    int d = threadIdx.x % 128;
    int s = src[e];
    int v = dst[e];
    atomicAdd(&msg[(size_t)v * 128 + d], node[(size_t)s * 128 + d]);
    if (d == 0) atomicAdd(&cnt[v], 1.0f);
}

// ---------------- per-step: gather x, prev_h, prev_c (pre-update) ----------------
__global__ void build_xh(const int* __restrict__ act, const float* __restrict__ node,
                         const float* __restrict__ cxp, const float* __restrict__ msg,
                         const float* __restrict__ cnt, float* __restrict__ xh,
                         float* __restrict__ pc) {
    int a = blockIdx.x * 2 + threadIdx.x / 128;
    int d = threadIdx.x % 128;
    int v = act[a];
    float ph = node[(size_t)v * 128 + d];
    float c = cnt[v];
    float ag = (c > 0.f) ? msg[(size_t)v * 128 + d] / c : 0.f;
    xh[(size_t)a * 256 + d] = ph + ag;        // x = node + agg
    xh[(size_t)a * 256 + 128 + d] = ph;       // prev_h
    pc[(size_t)a * 128 + d] = cxp[(size_t)v * 128 + d];
}

// ---------------- per-step: apply agg to node, re-zero msg/cnt ----------------
__global__ void apply_kernel(float* __restrict__ node, float* __restrict__ msg,
                             float* __restrict__ cnt) {
    int v = blockIdx.x * 2 + threadIdx.x / 128;
    int d = threadIdx.x % 128;
    float c = cnt[v];
    if (c > 0.f) {
        node[(size_t)v * 128 + d] += msg[(size_t)v * 128 + d] / c;
        msg[(size_t)v * 128 + d] = 0.f;
        if (d == 0) cnt[v] = 0.f;
    }
}

// ---------------- per-step: gates = XH(4096x256) @ Wcat^T(256x512) ----------------
__global__ __launch_bounds__(256) void gemm_gates(const float* __restrict__ xh,
                                                  const float* __restrict__ Wih,
                                                  const float* __restrict__ Whh,
                                                  float* __restrict__ gates) {
    __shared__ float As[16][64];
    __shared__ float Bs[16][64];
    int tid = threadIdx.x;
    int tx = tid % 16, ty = tid / 16;
    int m0 = blockIdx.x * 64;   // 64 tiles over M=4096
    int n0 = blockIdx.y * 64;   // 8 tiles over N=512
    float acc[4][4] = {};
    for (int k0 = 0; k0 < 256; k0 += 16) {
        {
            int r = tid / 4;
            int kk = (tid % 4) * 4;
            float4 v = *(const float4*)&xh[(size_t)(m0 + r) * 256 + k0 + kk];
            As[kk + 0][r] = v.x; As[kk + 1][r] = v.y; As[kk + 2][r] = v.z; As[kk + 3][r] = v.w;
        }
        {
            int n = tid / 4;
            int kk = (tid % 4) * 4;
            int kg = k0 + kk;
            const float* Wrow = (kg < 128) ? &Wih[(size_t)(n0 + n) * 128 + kg]
                                           : &Whh[(size_t)(n0 + n) * 128 + (kg - 128)];
            float4 v = *(const float4*)Wrow;
            Bs[kk + 0][n] = v.x; Bs[kk + 1][n] = v.y; Bs[kk + 2][n] = v.z; Bs[kk + 3][n] = v.w;
        }
        __syncthreads();
#pragma unroll
        for (int kk = 0; kk < 16; ++kk) {
            float4 av = *(const float4*)&As[kk][ty * 4];
            float4 bv = *(const float4*)&Bs[kk][tx * 4];
            float a[4] = {av.x, av.y, av.z, av.w};
            float b[4] = {bv.x, bv.y, bv.z, bv.w};
#pragma unroll
            for (int i = 0; i < 4; ++i)
#pragma unroll
                for (int j = 0; j < 4; ++j) acc[i][j] += a[i] * b[j];
        }
        __syncthreads();
    }
#pragma unroll
    for (int i = 0; i < 4; ++i) {
        float4 st = make_float4(acc[i][0], acc[i][1], acc[i][2], acc[i][3]);
        *(float4*)&gates[(size_t)(m0 + ty * 4 + i) * 512 + n0 + tx * 4] = st;
    }
}

// ---------------- per-step: LSTM epilogue ----------------
__global__ void lstm_epi(const float* __restrict__ gates, const float* __restrict__ bih,
                         const float* __restrict__ bhh, const float* __restrict__ pc,
                         const int* __restrict__ act, float* __restrict__ node,
                         float* __restrict__ cxp) {
    int a = blockIdx.x * 2 + threadIdx.x / 128;
    int d = threadIdx.x % 128;
    size_t g0 = (size_t)a * 512;
    float gi = gates[g0 + d]       + bih[d]       + bhh[d];
    float gf = gates[g0 + 128 + d] + bih[128 + d] + bhh[128 + d];
    float gg = gates[g0 + 256 + d] + bih[256 + d] + bhh[256 + d];
    float go = gates[g0 + 384 + d] + bih[384 + d] + bhh[384 + d];
    float i_ = 1.f / (1.f + __expf(-gi));
    float f_ = 1.f / (1.f + __expf(-gf));
    float g_ = tanhf(gg);
    float o_ = 1.f / (1.f + __expf(-go));
    float c_ = f_ * pc[(size_t)a * 128 + d] + i_ * g_;
    float h_ = o_ * tanhf(c_);
    int v = act[a];
    node[(size_t)v * 128 + d] = h_;
    cxp[(size_t)v * 128 + d] = c_;
}

// ---------------- per-step: snapshot rows whose seed_time == t ----------------
__global__ void snapshot_k(const float* __restrict__ node, const int* __restrict__ su,
                           const int* __restrict__ st, float* __restrict__ u_emb, int t) {
    int b = blockIdx.x * 2 + threadIdx.x / 128;
    int d = threadIdx.x % 128;
    if (st[b] == t) u_emb[(size_t)b * 128 + d] = node[(size_t)su[b] * 128 + d];
}

// ---------------- final: stabilized logsumexp over 49998 comps, two passes ----------------
// PASS 0: per-row max of dots -> m_ord (ordered-uint atomicMax)
// PASS 1: per-row sum of exp(dot - m) -> s_tot (atomicAdd)
template <int PASS>
__global__ __launch_bounds__(256) void lse_gemm(const float* __restrict__ u_emb,
                                                const float* __restrict__ ent,
                                                unsigned* __restrict__ m_ord,
                                                float* __restrict__ s_tot) {
    __shared__ float As[64][64];    // [k-chunk][b-row]
    __shared__ float Bs[64][64];    // [k-chunk][comp]
    __shared__ float red[64][16];
    int n0 = blockIdx.x * 64;       // 782 comp tiles
    int m0 = blockIdx.y * 64;       // 32 b tiles
    int tid = threadIdx.x;
    int tx = tid % 16, ty = tid / 16;
    float acc[4][4] = {};
    for (int k0 = 0; k0 < 128; k0 += 64) {
        for (int idx = tid; idx < 64 * 16; idx += 256) {
            int r = idx >> 4, kq = idx & 15;
            float4 v = *(const float4*)&u_emb[(size_t)(m0 + r) * 128 + k0 + kq * 4];
            As[kq * 4 + 0][r] = v.x; As[kq * 4 + 1][r] = v.y;
            As[kq * 4 + 2][r] = v.z; As[kq * 4 + 3][r] = v.w;
        }
        for (int idx = tid; idx < 64 * 16; idx += 256) {
            int r = idx >> 4, kq = idx & 15;
            int n = n0 + r;
            float4 v = make_float4(0.f, 0.f, 0.f, 0.f);
            if (n < COMPN) v = *(const float4*)&ent[(size_t)(USERN + n) * 128 + k0 + kq * 4];
            Bs[kq * 4 + 0][r] = v.x; Bs[kq * 4 + 1][r] = v.y;
            Bs[kq * 4 + 2][r] = v.z; Bs[kq * 4 + 3][r] = v.w;
        }
        __syncthreads();
#pragma unroll 8
        for (int k = 0; k < 64; ++k) {
            float4 av = *(const float4*)&As[k][ty * 4];
            float4 bv = *(const float4*)&Bs[k][tx * 4];
            float a[4] = {av.x, av.y, av.z, av.w};
            float b[4] = {bv.x, bv.y, bv.z, bv.w};
#pragma unroll
            for (int i = 0; i < 4; ++i)
#pragma unroll
                for (int j = 0; j < 4; ++j) acc[i][j] += a[i] * b[j];
        }
        __syncthreads();
    }
    if (PASS == 0) {
#pragma unroll
        for (int i = 0; i < 4; ++i) {
            float mx = -3.4e38f;
#pragma unroll
            for (int j = 0; j < 4; ++j)
                if (n0 + tx * 4 + j < COMPN) mx = fmaxf(mx, acc[i][j]);
            red[ty * 4 + i][tx] = mx;
        }
        __syncthreads();
        if (tid < 64) {
            float mx = red[tid][0];
#pragma unroll
            for (int x = 1; x < 16; ++x) mx = fmaxf(mx, red[tid][x]);
            atomicMax(&m_ord[m0 + tid], floatToOrd(mx));
        }
    } else {
#pragma unroll
        for (int i = 0; i < 4; ++i) {
            float m = ordToFloat(m_ord[m0 + ty * 4 + i]);
            float rs = 0.f;
#pragma unroll
            for (int j = 0; j < 4; ++j)
                if (n0 + tx * 4 + j < COMPN) rs += __expf(acc[i][j] - m);
            red[ty * 4 + i][tx] = rs;
        }
        __syncthreads();
        if (tid < 64) {
            float s = 0.f;
#pragma unroll
            for (int x = 0; x < 16; ++x) s += red[tid][x];
            atomicAdd(&s_tot[m0 + tid], s);
        }
    }
}

// ---------------- final: loss = sum_b (m + log(s_tot) - pos) ----------------
__global__ void final_k(const float* __restrict__ u_emb, const float* __restrict__ ent,
                        const int* __restrict__ crel, const float* __restrict__ s_tot,
                        const unsigned* __restrict__ m_ord, float* __restrict__ out) {
    int b = blockIdx.x * 256 + threadIdx.x;
    if (b >= BB) return;
    float lse = ordToFloat(m_ord[b]) + logf(s_tot[b]);
    const float* u = &u_emb[(size_t)b * 128];
    const float* c = &ent[(size_t)(USERN + crel[b]) * 128];
    float pos = 0.f;
#pragma unroll
    for (int k = 0; k < 128; k += 4) {
        float4 uv = *(const float4*)&u[k];
        float4 cv = *(const float4*)&c[k];
        pos += uv.x * cv.x + uv.y * cv.y + uv.z * cv.z + uv.w * cv.w;
    }
    atomicAdd(out, lse - pos);
}

extern "C" void kernel_launch(void* const* d_in, const int* in_sizes, int n_in,
                              void* d_out, int out_size, void* d_ws, size_t ws_size,
                              hipStream_t stream) {
    const float* ent  = (const float*)d_in[0];
    const float* c0   = (const float*)d_in[1];
    const float* Wih  = (const float*)d_in[2];
    const float* Whh  = (const float*)d_in[3];
    const float* bih  = (const float*)d_in[4];
    const float* bhh  = (const float*)d_in[5];
    const int* esrc   = (const int*)d_in[6];
    const int* edst   = (const int*)d_in[7];
    const int* act    = (const int*)d_in[8];
    const int* susr   = (const int*)d_in[9];
    const int* stime  = (const int*)d_in[10];
    const int* crel   = (const int*)d_in[11];
    float* out = (float*)d_out;

    float* ws = (float*)d_ws;
    size_t o = 0;
    float* node  = ws + o; o += (size_t)NNODE * EMBD;   // 25.6M
    float* cxp   = ws + o; o += (size_t)NNODE * EMBD;   // 25.6M
    float* msg   = ws + o; o += (size_t)NNODE * EMBD;   // 25.6M
    float* xh    = ws + o; o += (size_t)AA * 256;
    float* pc    = ws + o; o += (size_t)AA * 128;
    float* gates = ws + o; o += (size_t)AA * 512;
    float* u_emb = ws + o; o += (size_t)BB * 128;
    float* s_tot = ws + o; o += (size_t)BB;
    unsigned* m_ord = (unsigned*)(ws + o); o += (size_t)BB;
    float* cnt   = ws + o; o += (size_t)NNODE;
    // total ~81M floats = ~324 MB

    init_kernel<<<2048, 256, 0, stream>>>((const float4*)ent, (const float4*)c0,
                                          (float4*)node, (float4*)cxp, (float4*)msg,
                                          cnt, s_tot, m_ord, out);

    for (int t = 0; t < TT; ++t) {
        const int* src_t = esrc + (size_t)t * EE;
        const int* dst_t = edst + (size_t)t * EE;
        const int* act_t = act + (size_t)t * AA;
        edge_kernel<<<EE / 2, 256, 0, stream>>>(src_t, dst_t, node, msg, cnt);
        build_xh<<<AA / 2, 256, 0, stream>>>(act_t, node, cxp, msg, cnt, xh, pc);
        apply_kernel<<<NNODE / 2, 256, 0, stream>>>(node, msg, cnt);
        gemm_gates<<<dim3(64, 8), 256, 0, stream>>>(xh, Wih, Whh, gates);
        lstm_epi<<<AA / 2, 256, 0, stream>>>(gates, bih, bhh, pc, act_t, node, cxp);
        snapshot_k<<<BB / 2, 256, 0, stream>>>(node, susr, stime, u_emb, t);
    }

    lse_gemm<0><<<dim3((COMPN + 63) / 64, BB / 64), 256, 0, stream>>>(u_emb, ent, m_ord, s_tot);
    lse_gemm<1><<<dim3((COMPN + 63) / 64, BB / 64), 256, 0, stream>>>(u_emb, ent, m_ord, s_tot);
    final_k<<<BB / 256, 256, 0, stream>>>(u_emb, ent, crel, s_tot, m_ord, out);
}

// Round 3
// 4657.259 us; speedup vs baseline: 1.1112x; 1.1112x over previous
//
#include <hip/hip_runtime.h>
#include <hip/hip_bf16.h>
#include <math.h>

#define NNODE 200000
#define EMBD  128
#define TT    32
#define EE    100000
#define AA    4096
#define BB    2048
#define USERN 150000
#define COMPN 49998
#define NTILE 782   // ceil(49998/64)

// ---------------- init ----------------
__global__ void init_kernel(const float4* __restrict__ ent, const float4* __restrict__ c0,
                            float4* __restrict__ node, float4* __restrict__ cxp,
                            float4* __restrict__ msg, float* __restrict__ cnt,
                            float* __restrict__ out) {
    const long NV = (long)NNODE * EMBD / 4;  // 6.4M float4
    long i0 = (long)blockIdx.x * blockDim.x + threadIdx.x;
    long stride = (long)gridDim.x * blockDim.x;
    float4 z = make_float4(0.f, 0.f, 0.f, 0.f);
    for (long i = i0; i < NV; i += stride) { node[i] = ent[i]; cxp[i] = c0[i]; msg[i] = z; }
    for (long i = i0; i < NNODE; i += stride) cnt[i] = 0.f;
    if (i0 == 0) out[0] = 0.f;
}

// ---------------- per-step: edge scatter ----------------
__global__ void edge_kernel(const int* __restrict__ src, const int* __restrict__ dst,
                            const float* __restrict__ node, float* __restrict__ msg,
                            float* __restrict__ cnt) {
    int e = blockIdx.x * 2 + threadIdx.x / 128;
    int d = threadIdx.x % 128;
    int s = src[e];
    int v = dst[e];
    atomicAdd(&msg[(size_t)v * 128 + d], node[(size_t)s * 128 + d]);
    if (d == 0) atomicAdd(&cnt[v], 1.0f);
}

// ---------------- per-step: gather x, prev_h, prev_c (pre-update) ----------------
__global__ void build_xh(const int* __restrict__ act, const float* __restrict__ node,
                         const float* __restrict__ cxp, const float* __restrict__ msg,
                         const float* __restrict__ cnt, float* __restrict__ xh,
                         float* __restrict__ pc) {
    int a = blockIdx.x * 2 + threadIdx.x / 128;
    int d = threadIdx.x % 128;
    int v = act[a];
    float ph = node[(size_t)v * 128 + d];
    float c = cnt[v];
    float ag = (c > 0.f) ? msg[(size_t)v * 128 + d] / c : 0.f;
    xh[(size_t)a * 256 + d] = ph + ag;        // x = node + agg
    xh[(size_t)a * 256 + 128 + d] = ph;       // prev_h
    pc[(size_t)a * 128 + d] = cxp[(size_t)v * 128 + d];
}

// ---------------- per-step: apply agg to node, re-zero msg/cnt ----------------
__global__ void apply_kernel(float* __restrict__ node, float* __restrict__ msg,
                             float* __restrict__ cnt) {
    int v = blockIdx.x * 2 + threadIdx.x / 128;
    int d = threadIdx.x % 128;
    float c = cnt[v];
    if (c > 0.f) {
        node[(size_t)v * 128 + d] += msg[(size_t)v * 128 + d] / c;
        msg[(size_t)v * 128 + d] = 0.f;
        if (d == 0) cnt[v] = 0.f;
    }
}

// ---------------- per-step: gates = XH(4096x256) @ Wcat^T(256x512) ----------------
__global__ __launch_bounds__(256) void gemm_gates(const float* __restrict__ xh,
                                                  const float* __restrict__ Wih,
                                                  const float* __restrict__ Whh,
                                                  float* __restrict__ gates) {
    __shared__ float As[16][64];
    __shared__ float Bs[16][64];
    int tid = threadIdx.x;
    int tx = tid % 16, ty = tid / 16;
    int m0 = blockIdx.x * 64;   // 64 tiles over M=4096
    int n0 = blockIdx.y * 64;   // 8 tiles over N=512
    float acc[4][4] = {};
    for (int k0 = 0; k0 < 256; k0 += 16) {
        {
            // conflict-free staging: wave lanes cover 64 distinct rows
            int r = tid & 63;
            int kq = tid >> 6;   // 0..3
            float4 v = *(const float4*)&xh[(size_t)(m0 + r) * 256 + k0 + kq * 4];
            As[kq * 4 + 0][r] = v.x; As[kq * 4 + 1][r] = v.y;
            As[kq * 4 + 2][r] = v.z; As[kq * 4 + 3][r] = v.w;
        }
        {
            int n = tid & 63;
            int kq = tid >> 6;
            int kg = k0 + kq * 4;
            const float* Wrow = (kg < 128) ? &Wih[(size_t)(n0 + n) * 128 + kg]
                                           : &Whh[(size_t)(n0 + n) * 128 + (kg - 128)];
            float4 v = *(const float4*)Wrow;
            Bs[kq * 4 + 0][n] = v.x; Bs[kq * 4 + 1][n] = v.y;
            Bs[kq * 4 + 2][n] = v.z; Bs[kq * 4 + 3][n] = v.w;
        }
        __syncthreads();
#pragma unroll
        for (int kk = 0; kk < 16; ++kk) {
            float4 av = *(const float4*)&As[kk][ty * 4];
            float4 bv = *(const float4*)&Bs[kk][tx * 4];
            float a[4] = {av.x, av.y, av.z, av.w};
            float b[4] = {bv.x, bv.y, bv.z, bv.w};
#pragma unroll
            for (int i = 0; i < 4; ++i)
#pragma unroll
                for (int j = 0; j < 4; ++j) acc[i][j] += a[i] * b[j];
        }
        __syncthreads();
    }
#pragma unroll
    for (int i = 0; i < 4; ++i) {
        float4 st = make_float4(acc[i][0], acc[i][1], acc[i][2], acc[i][3]);
        *(float4*)&gates[(size_t)(m0 + ty * 4 + i) * 512 + n0 + tx * 4] = st;
    }
}

// ---------------- per-step: LSTM epilogue ----------------
__global__ void lstm_epi(const float* __restrict__ gates, const float* __restrict__ bih,
                         const float* __restrict__ bhh, const float* __restrict__ pc,
                         const int* __restrict__ act, float* __restrict__ node,
                         float* __restrict__ cxp) {
    int a = blockIdx.x * 2 + threadIdx.x / 128;
    int d = threadIdx.x % 128;
    size_t g0 = (size_t)a * 512;
    float gi = gates[g0 + d]       + bih[d]       + bhh[d];
    float gf = gates[g0 + 128 + d] + bih[128 + d] + bhh[128 + d];
    float gg = gates[g0 + 256 + d] + bih[256 + d] + bhh[256 + d];
    float go = gates[g0 + 384 + d] + bih[384 + d] + bhh[384 + d];
    float i_ = 1.f / (1.f + __expf(-gi));
    float f_ = 1.f / (1.f + __expf(-gf));
    float g_ = tanhf(gg);
    float o_ = 1.f / (1.f + __expf(-go));
    float c_ = f_ * pc[(size_t)a * 128 + d] + i_ * g_;
    float h_ = o_ * tanhf(c_);
    int v = act[a];
    node[(size_t)v * 128 + d] = h_;
    cxp[(size_t)v * 128 + d] = c_;
}

// ---------------- per-step: snapshot rows whose seed_time == t ----------------
__global__ void snapshot_k(const float* __restrict__ node, const int* __restrict__ su,
                           const int* __restrict__ st, float* __restrict__ u_emb, int t) {
    int b = blockIdx.x * 2 + threadIdx.x / 128;
    int d = threadIdx.x % 128;
    if (st[b] == t) u_emb[(size_t)b * 128 + d] = node[(size_t)su[b] * 128 + d];
}

// ---------------- final: single-pass online LSE partials (per 64x64 tile) ----------------
__global__ __launch_bounds__(256) void lse_onepass(const float* __restrict__ u_emb,
                                                   const float* __restrict__ ent,
                                                   float* __restrict__ pm,
                                                   float* __restrict__ ps) {
    __shared__ float As[64][64];    // [k][b-row]
    __shared__ float Bs[64][64];    // [k][comp]
    __shared__ float red[64][16];
    __shared__ float mrow[64];
    int n0 = blockIdx.x * 64;       // 782 comp tiles
    int m0 = blockIdx.y * 64;       // 32 b tiles
    int tid = threadIdx.x;
    int tx = tid % 16, ty = tid / 16;
    float acc[4][4] = {};
    for (int k0 = 0; k0 < 128; k0 += 64) {
        {
            // conflict-free staging: r = lane (64 distinct rows per wave)
            int r = tid & 63;
            for (int kq = tid >> 6; kq < 16; kq += 4) {
                float4 v = *(const float4*)&u_emb[(size_t)(m0 + r) * 128 + k0 + kq * 4];
                As[kq * 4 + 0][r] = v.x; As[kq * 4 + 1][r] = v.y;
                As[kq * 4 + 2][r] = v.z; As[kq * 4 + 3][r] = v.w;
            }
        }
        {
            int r = tid & 63;
            int n = n0 + r;
            for (int kq = tid >> 6; kq < 16; kq += 4) {
                float4 v = make_float4(0.f, 0.f, 0.f, 0.f);
                if (n < COMPN) v = *(const float4*)&ent[(size_t)(USERN + n) * 128 + k0 + kq * 4];
                Bs[kq * 4 + 0][r] = v.x; Bs[kq * 4 + 1][r] = v.y;
                Bs[kq * 4 + 2][r] = v.z; Bs[kq * 4 + 3][r] = v.w;
            }
        }
        __syncthreads();
#pragma unroll 8
        for (int k = 0; k < 64; ++k) {
            float4 av = *(const float4*)&As[k][ty * 4];
            float4 bv = *(const float4*)&Bs[k][tx * 4];
            float a[4] = {av.x, av.y, av.z, av.w};
            float b[4] = {bv.x, bv.y, bv.z, bv.w};
#pragma unroll
            for (int i = 0; i < 4; ++i)
#pragma unroll
                for (int j = 0; j < 4; ++j) acc[i][j] += a[i] * b[j];
        }
        __syncthreads();
    }
    // block-local row max
#pragma unroll
    for (int i = 0; i < 4; ++i) {
        float mx = -3.4e38f;
#pragma unroll
        for (int j = 0; j < 4; ++j)
            if (n0 + tx * 4 + j < COMPN) mx = fmaxf(mx, acc[i][j]);
        red[ty * 4 + i][tx] = mx;
    }
    __syncthreads();
    if (tid < 64) {
        float mx = red[tid][0];
#pragma unroll
        for (int x = 1; x < 16; ++x) mx = fmaxf(mx, red[tid][x]);
        mrow[tid] = mx;
    }
    __syncthreads();
    // block-local sum of exp(dot - m_blk)
#pragma unroll
    for (int i = 0; i < 4; ++i) {
        float m = mrow[ty * 4 + i];
        float rs = 0.f;
#pragma unroll
        for (int j = 0; j < 4; ++j)
            if (n0 + tx * 4 + j < COMPN) rs += __expf(acc[i][j] - m);
        red[ty * 4 + i][tx] = rs;
    }
    __syncthreads();
    if (tid < 64) {
        float s = 0.f;
#pragma unroll
        for (int x = 0; x < 16; ++x) s += red[tid][x];
        pm[(size_t)blockIdx.x * BB + m0 + tid] = mrow[tid];
        ps[(size_t)blockIdx.x * BB + m0 + tid] = s;
    }
}

// ---------------- final: merge per-tile partials into lse per row ----------------
__global__ void lse_merge(const float* __restrict__ pm, const float* __restrict__ ps,
                          float* __restrict__ lse_row) {
    int row = blockIdx.x * 256 + threadIdx.x;   // 8 blocks x 256 = 2048
    float m = -3.4e38f, s = 0.f;
    for (int c = 0; c < NTILE; ++c) {
        float mi = pm[(size_t)c * BB + row];
        float si = ps[(size_t)c * BB + row];
        if (mi > m) { s = s * __expf(m - mi) + si; m = mi; }
        else        { s += si * __expf(mi - m); }
    }
    lse_row[row] = m + logf(s);
}

// ---------------- final: loss = sum_b (lse - pos) ----------------
__global__ void final_k(const float* __restrict__ u_emb, const float* __restrict__ ent,
                        const int* __restrict__ crel, const float* __restrict__ lse_row,
                        float* __restrict__ out) {
    int b = blockIdx.x * 256 + threadIdx.x;
    if (b >= BB) return;
    float lse = lse_row[b];
    const float* u = &u_emb[(size_t)b * 128];
    const float* c = &ent[(size_t)(USERN + crel[b]) * 128];
    float pos = 0.f;
#pragma unroll
    for (int k = 0; k < 128; k += 4) {
        float4 uv = *(const float4*)&u[k];
        float4 cv = *(const float4*)&c[k];
        pos += uv.x * cv.x + uv.y * cv.y + uv.z * cv.z + uv.w * cv.w;
    }
    atomicAdd(out, lse - pos);
}

extern "C" void kernel_launch(void* const* d_in, const int* in_sizes, int n_in,
                              void* d_out, int out_size, void* d_ws, size_t ws_size,
                              hipStream_t stream) {
    const float* ent  = (const float*)d_in[0];
    const float* c0   = (const float*)d_in[1];
    const float* Wih  = (const float*)d_in[2];
    const float* Whh  = (const float*)d_in[3];
    const float* bih  = (const float*)d_in[4];
    const float* bhh  = (const float*)d_in[5];
    const int* esrc   = (const int*)d_in[6];
    const int* edst   = (const int*)d_in[7];
    const int* act    = (const int*)d_in[8];
    const int* susr   = (const int*)d_in[9];
    const int* stime  = (const int*)d_in[10];
    const int* crel   = (const int*)d_in[11];
    float* out = (float*)d_out;

    float* ws = (float*)d_ws;
    size_t o = 0;
    float* node  = ws + o; o += (size_t)NNODE * EMBD;   // 25.6M
    float* cxp   = ws + o; o += (size_t)NNODE * EMBD;   // 25.6M
    float* msg   = ws + o; o += (size_t)NNODE * EMBD;   // 25.6M
    float* xh    = ws + o; o += (size_t)AA * 256;
    float* pc    = ws + o; o += (size_t)AA * 128;
    float* gates = ws + o; o += (size_t)AA * 512;
    float* u_emb = ws + o; o += (size_t)BB * 128;
    float* lse_row = ws + o; o += (size_t)BB;
    float* cnt   = ws + o; o += (size_t)NNODE;
    // lse partials reuse msg (idle after the loop; re-zeroed by init each launch)
    float* pm = msg;                       // [NTILE][BB]
    float* ps = msg + (size_t)NTILE * BB;  // [NTILE][BB]

    init_kernel<<<2048, 256, 0, stream>>>((const float4*)ent, (const float4*)c0,
                                          (float4*)node, (float4*)cxp, (float4*)msg,
                                          cnt, out);

    for (int t = 0; t < TT; ++t) {
        const int* src_t = esrc + (size_t)t * EE;
        const int* dst_t = edst + (size_t)t * EE;
        const int* act_t = act + (size_t)t * AA;
        edge_kernel<<<EE / 2, 256, 0, stream>>>(src_t, dst_t, node, msg, cnt);
        build_xh<<<AA / 2, 256, 0, stream>>>(act_t, node, cxp, msg, cnt, xh, pc);
        apply_kernel<<<NNODE / 2, 256, 0, stream>>>(node, msg, cnt);
        gemm_gates<<<dim3(64, 8), 256, 0, stream>>>(xh, Wih, Whh, gates);
        lstm_epi<<<AA / 2, 256, 0, stream>>>(gates, bih, bhh, pc, act_t, node, cxp);
        snapshot_k<<<BB / 2, 256, 0, stream>>>(node, susr, stime, u_emb, t);
    }

    lse_onepass<<<dim3(NTILE, BB / 64), 256, 0, stream>>>(u_emb, ent, pm, ps);
    lse_merge<<<BB / 256, 256, 0, stream>>>(pm, ps, lse_row);
    final_k<<<BB / 256, 256, 0, stream>>>(u_emb, ent, crel, lse_row, out);
}